// Round 1
// baseline (514.808 us; speedup 1.0000x reference)
//
#include <hip/hip_runtime.h>

#define THETA_DIM 11
#define BQ   16      // chains per block (block = 1 wave, 4 lanes per chain)
#define TILE 64      // time steps staged per tile
#define EPAD 68      // padded LDS row stride (floats): 16B-aligned, <=2-way banks

// ---- quad (4-lane) cross-lane ops via DPP quad_perm (VALU pipe, no LDS) ----
__device__ __forceinline__ float qdpp_b1(float v) {   // [1,0,3,2]
  return __builtin_bit_cast(float,
      __builtin_amdgcn_update_dpp(0, __builtin_bit_cast(int, v), 0xB1, 0xF, 0xF, true));
}
__device__ __forceinline__ float qdpp_4e(float v) {   // [2,3,0,1]
  return __builtin_bit_cast(float,
      __builtin_amdgcn_update_dpp(0, __builtin_bit_cast(int, v), 0x4E, 0xF, 0xF, true));
}
__device__ __forceinline__ float quad_max(float v) {
  v = fmaxf(v, qdpp_b1(v));
  v = fmaxf(v, qdpp_4e(v));
  return v;
}
__device__ __forceinline__ float quad_sum(float v) {
  v = v + qdpp_b1(v);
  v = v + qdpp_4e(v);
  return v;
}
__device__ __forceinline__ float exp2_fast(float x) {  // single v_exp_f32
  float r;
  asm("v_exp_f32 %0, %1" : "=v"(r) : "v"(x));
  return r;
}

// One recurrence step. State x1,x2,x3; Rx2/blRx2/q are precomputed from older
// state (off the serial critical path). All 4 lanes of a quad hold identical
// scalar state; the j-indexed quantities (g, b) live one-per-lane.
__device__ __forceinline__ float bh_step(
    float e, float& x1, float& x2, float& x3,
    float& Rx2, float& blRx2, float& q,
    float bl2e, float bl2eR, float R, float g, float bb,
    float gR, float bR, float sR) {
  const float A   = fmaf(bl2e, x1, -blRx2);  // beta*log2e*(x1 - R*x2)
  const float tj  = A * q;                   // exponent in log2 domain (lane j)
  const float m   = quad_max(tj);
  const float p   = exp2_fast(tj - m);       // unnormalized softmax weight
  const float cc  = fmaf(gR, x1, bR);        // (g*x1 + b)/R  (1/R folded in)
  const float num = quad_sum(p * cc);
  const float den = quad_sum(p);             // in [1,4] since max lane gives p=1
  const float invden = __builtin_amdgcn_rcpf(den);
  const float es  = e * sR;                  // eps*sigma/R
  const float x   = fmaf(num, invden, es);
  x3 = x2; x2 = x1; x1 = x;
  // precompute for next step (depends only on new x2=old x1, new x3=old x2)
  Rx2   = R * x2;
  blRx2 = bl2eR * x2;                        // beta*log2e*R*x2
  q     = fmaf(g, x3, bb) - Rx2;             // g*x3 + b - R*x2
  return x;
}

__global__ void __launch_bounds__(64, 1)
bh_kernel(const float* __restrict__ theta, const float* __restrict__ eps,
          float* __restrict__ out, int Tn) {
  __shared__ float eps_s[2][BQ][EPAD];   // double-buffered eps tile
  __shared__ float out_s[BQ][EPAD];      // output tile

  const int lane = threadIdx.x;
  const int c  = lane >> 2;          // chain within block (0..15)
  const int j  = lane & 3;           // softmax component (0..3)
  const int cb = blockIdx.x * BQ;    // first chain of block
  const int b  = cb + c;

  const float* th = theta + b * THETA_DIM;
  const float beta = th[0];
  const float g    = th[1 + j];
  const float bb   = th[5 + j];
  const float sig  = th[9];
  const float r    = th[10];
  const float R    = 1.0f + r;
  const float invR = 1.0f / R;                   // exact, once
  const float L2E  = 1.4426950408889634f;
  const float bl2e = beta * L2E;
  const float bl2eR = bl2e * R;
  const float gR = g * invR;
  const float bR = bb * invR;
  const float sR = sig * invR;

  // staging lane mapping: 16 lanes x float4 cover one row (64 floats); 4 rows/instr
  const int col  = lane & 15;
  const int rsub = lane >> 4;

  const int NT = Tn / TILE;

  // prologue: stage tile 0 into buffer 0 (coalesced float4)
  #pragma unroll
  for (int i = 0; i < 4; ++i) {
    const float4 v = *(const float4*)(eps + (size_t)(cb + i*4 + rsub) * Tn + col*4);
    *(float4*)&eps_s[0][i*4 + rsub][col*4] = v;
  }

  float x1 = 0.f, x2 = 0.f, x3 = 0.f;
  float Rx2 = 0.f, blRx2 = 0.f, q = bb;  // consistent with x2=x3=0

  const bool j0 = (j == 0), j1 = (j == 1), j2 = (j == 2);

  for (int tile = 0; tile < NT; ++tile) {
    const int buf = tile & 1;
    const int t0  = tile * TILE;
    const bool more = (tile + 1 < NT);

    // issue next tile's global loads NOW; consume (LDS write) after compute,
    // so the vmcnt wait is hidden behind ~3500 cycles of recurrence work.
    float4 pre[4];
    if (more) {
      #pragma unroll
      for (int i = 0; i < 4; ++i)
        pre[i] = *(const float4*)(eps + (size_t)(cb + i*4 + rsub) * Tn
                                  + (t0 + TILE) + col*4);
    }

    const float* ec = &eps_s[buf][c][0];
    float* oc = &out_s[c][0];

    #pragma unroll 4
    for (int t4 = 0; t4 < TILE/4; ++t4) {
      const float4 e4 = *(const float4*)(ec + t4*4);  // ds_read_b128, quad-broadcast
      const float xw0 = bh_step(e4.x, x1,x2,x3, Rx2,blRx2,q, bl2e,bl2eR,R,g,bb,gR,bR,sR);
      const float xw1 = bh_step(e4.y, x1,x2,x3, Rx2,blRx2,q, bl2e,bl2eR,R,g,bb,gR,bR,sR);
      const float xw2 = bh_step(e4.z, x1,x2,x3, Rx2,blRx2,q, bl2e,bl2eR,R,g,bb,gR,bR,sR);
      const float xw3 = bh_step(e4.w, x1,x2,x3, Rx2,blRx2,q, bl2e,bl2eR,R,g,bb,gR,bR,sR);
      // lane j stores step (4*t4+j): 1 ds_write + 3 cndmask per 4 steps, no divergence
      const float xw = j0 ? xw0 : (j1 ? xw1 : (j2 ? xw2 : xw3));
      oc[t4*4 + j] = xw;
    }

    // writeback output tile (coalesced float4 stores)
    #pragma unroll
    for (int i = 0; i < 4; ++i) {
      const float4 o4 = *(const float4*)&out_s[i*4 + rsub][col*4];
      *(float4*)(out + (size_t)(cb + i*4 + rsub) * Tn + t0 + col*4) = o4;
    }

    // deposit prefetched eps into the other buffer (vmcnt wait lands here)
    if (more) {
      #pragma unroll
      for (int i = 0; i < 4; ++i)
        *(float4*)&eps_s[buf ^ 1][i*4 + rsub][col*4] = pre[i];
    }
  }
}

extern "C" void kernel_launch(void* const* d_in, const int* in_sizes, int n_in,
                              void* d_out, int out_size, void* d_ws, size_t ws_size,
                              hipStream_t stream) {
  const float* theta = (const float*)d_in[0];
  const float* eps   = (const float*)d_in[1];
  float* out = (float*)d_out;
  const int B  = in_sizes[0] / THETA_DIM;   // 8192
  const int Tn = in_sizes[1] / B;           // 4096
  const int blocks = B / BQ;                // 512 blocks x 64 threads (1 wave each)
  bh_kernel<<<blocks, 64, 0, stream>>>(theta, eps, out, Tn);
}